// Round 4
// baseline (647.749 us; speedup 1.0000x reference)
//
#include <hip/hip_runtime.h>

// SelfAttention (Galerkin linear attention), round 6.
// Algebra: qk_in = x + pos ; K = qk_in Wk^T + bk ; V = x Wv^T + bv
//          (per-head LN on K,V) ; S'_h = K_h^T V_h / n
//          W2[he][r] = sum_d Wq[hd][r] S'[d][e] ; b2[he] = sum_d bq[hd] S'[d][e]
//          out = LN(2*(qk_in W2^T + b2)) stored NCHW.
// R5 insight kept: pos is separable -> f32 tables PyK[i][oc], PxK[j][oc],
//   Py2[i][e], Px2[e][j]; only xT=bf16(x) is staged (XOR-swizzled for
//   global_load_lds + conflict-free ds_read_b128).
// R6 (this round): kv_scores was LDS-pipe bound on the LN shuffle reduce
//   (512 ds_swizzle per wave per n-tile vs 512 MFMA total). Fix:
//   1) SWAPPED MFMA operands (A=W frags, B=x frags) -> D[oc][n]: a head's 32
//      channels are 8 in-lane regs x 4 l4-lanes -> LN = in-lane adds + 2
//      shfl_xor(16,32). 8x fewer shuffles.
//   2) KT/VT relayout is wave-private (rows w*32..+32) -> all relayout
//      barriers removed; writes are ds_write_b16 scatters (~2-way, free).
//   3) NT=2 -> grid (64,2,8)=1024 blocks (3 blocks/CU at 52KB LDS).
//   4) s_setprio(1) around the K/V MFMA burst.
//   PxK re-laid [j][oc] (poswk); Px2 layout unchanged (out_kernel keeps the
//   n-coalesced store orientation, its LN is cheap).

typedef float floatx4 __attribute__((ext_vector_type(4)));
typedef __bf16 bf16x8 __attribute__((ext_vector_type(8)));
typedef unsigned short ushortx8 __attribute__((ext_vector_type(8)));
typedef unsigned short ushort;

static __device__ __forceinline__ ushort f2bf(float f) {
  unsigned int u = __builtin_bit_cast(unsigned int, f);
  u += 0x7FFFu + ((u >> 16) & 1u);  // RNE
  return (ushort)(u >> 16);
}
static __device__ __forceinline__ floatx4 mfma16(bf16x8 a, bf16x8 b, floatx4 c) {
  return __builtin_amdgcn_mfma_f32_16x16x32_bf16(a, b, c, 0, 0, 0);
}
static __device__ __forceinline__ bf16x8 frag(const ushort* p) {
  return *(const bf16x8*)p;  // 16-B aligned by construction -> dwordx4
}
typedef __attribute__((address_space(3))) unsigned int as3_u32;
typedef __attribute__((address_space(1))) const unsigned int as1_u32;
static __device__ __forceinline__ void gl_lds16(const ushort* g, ushort* l) {
  __builtin_amdgcn_global_load_lds((as1_u32*)g, (as3_u32*)l, 16, 0, 0);
}

// ---------------------------------------------------------------------------
// Wk, Wv fp32 -> bf16 (plain [oc][256]).
__global__ __launch_bounds__(256) void prep_w(const float* __restrict__ Wk,
                                              const float* __restrict__ Wv,
                                              ushort* __restrict__ Wkbf,
                                              ushort* __restrict__ Wvbf) {
  const int i = (int)blockIdx.x * 256 + (int)threadIdx.x;
  float4 a = ((const float4*)Wk)[i];
  float4 b = ((const float4*)Wv)[i];
  ushort4 ua = {f2bf(a.x), f2bf(a.y), f2bf(a.z), f2bf(a.w)};
  ushort4 ub = {f2bf(b.x), f2bf(b.y), f2bf(b.z), f2bf(b.w)};
  ((ushort4*)Wkbf)[i] = ua;
  ((ushort4*)Wvbf)[i] = ub;
}

// ---------------------------------------------------------------------------
// Pos tables for K: PyKb[i][oc] = bk[oc] + sum_{kk<128} pe(i,kk)*Wk[oc][kk]
//                   PxKj[j][oc] =          sum_{kk<128} pe(j,kk)*Wk[oc][128+kk]
__global__ __launch_bounds__(256) void poswk(const float* __restrict__ Wk,
                                             const float* __restrict__ bk,
                                             float* __restrict__ PyKb,
                                             float* __restrict__ PxKj) {
  __shared__ float pe[128];
  const int ii = (int)blockIdx.x, t = (int)threadIdx.x;
  if (t < 128) {
    const float coord = (float)(ii + 1) * (6.283185307179586f / (128.0f + 1e-6f));
    const float inv = exp2f(-13.287712379549449f * (float)(t >> 1) * (1.0f / 64.0f));
    const float arg = coord * inv;
    pe[t] = (t & 1) ? cosf(arg) : sinf(arg);
  }
  __syncthreads();
  const float* wrow = Wk + (size_t)t * 256;
  float py = bk[t], px = 0.0f;
#pragma unroll 8
  for (int kk = 0; kk < 128; ++kk) {
    py += pe[kk] * wrow[kk];
    px += pe[kk] * wrow[128 + kk];
  }
  PyKb[ii * 256 + t] = py;
  PxKj[ii * 256 + t] = px;  // [j][oc] layout (R6)
}

// ---------------------------------------------------------------------------
// Pos tables for W2 (per z): Py2b[z][i][e] = b2[z][e] + pos_y(i) @ W2f[z][e][:128]
//                            Px2T[z][e][j] =            pos_x(j) @ W2f[z][e][128:]
__global__ __launch_bounds__(256) void posw2(const float* __restrict__ W2f,
                                             const float* __restrict__ b2,
                                             float* __restrict__ Py2b,
                                             float* __restrict__ Px2T) {
  __shared__ float pe[128];
  const int ii = (int)blockIdx.x, z = (int)blockIdx.y, t = (int)threadIdx.x;
  if (t < 128) {
    const float coord = (float)(ii + 1) * (6.283185307179586f / (128.0f + 1e-6f));
    const float inv = exp2f(-13.287712379549449f * (float)(t >> 1) * (1.0f / 64.0f));
    const float arg = coord * inv;
    pe[t] = (t & 1) ? cosf(arg) : sinf(arg);
  }
  __syncthreads();
  const float* wrow = W2f + (size_t)z * 65536 + (size_t)t * 256;
  float py = b2[z * 256 + t], px = 0.0f;
#pragma unroll 8
  for (int kk = 0; kk < 128; ++kk) {
    py += pe[kk] * wrow[kk];
    px += pe[kk] * wrow[128 + kk];
  }
  Py2b[((size_t)z * 128 + ii) * 256 + t] = py;
  Px2T[(size_t)z * 32768 + t * 128 + ii] = px;
}

// ---------------------------------------------------------------------------
// For batch b0+z: xT[z][n][k] = bf16(x). SWIZZLED store: 16B sub-chunk p
// stored at p ^ (n&7) within each 64-k group.
__global__ __launch_bounds__(256) void prep_qx(const float* __restrict__ x,
                                               ushort* __restrict__ xT, int b0) {
  __shared__ float tile[64 * 68];
  const int t = (int)threadIdx.x;
  const int z = (int)blockIdx.y;
  const int b = b0 + z;
  const int n0 = (int)blockIdx.x * 64;
  const float* xb = x + (size_t)b * 256 * 16384;
  ushort* xtb = xT + (size_t)z * 16384 * 256;
  for (int kc = 0; kc < 4; ++kc) {
    if (kc) __syncthreads();
    const int nn = (t & 15) * 4;
    const int r0 = t >> 4;
#pragma unroll
    for (int it = 0; it < 4; ++it) {
      const int k = r0 + it * 16;
      const float4 v = *(const float4*)(xb + (size_t)(kc * 64 + k) * 16384 + n0 + nn);
      tile[(nn + 0) * 68 + k] = v.x;
      tile[(nn + 1) * 68 + k] = v.y;
      tile[(nn + 2) * 68 + k] = v.z;
      tile[(nn + 3) * 68 + k] = v.w;
    }
    __syncthreads();
#pragma unroll
    for (int it = 0; it < 2; ++it) {
      const int P = t + it * 256;
      const int r = P >> 3;  // n row 0..63
      const int p = P & 7;   // k chunk of 8
      const int n = n0 + r;
      ushortx8 ux;
#pragma unroll
      for (int e = 0; e < 8; ++e) ux[e] = f2bf(tile[r * 68 + p * 8 + e]);
      const int sw = (p ^ (r & 7)) * 8;
      *(ushortx8*)(xtb + (size_t)n * 256 + kc * 64 + sw) = ux;
    }
  }
}

// ---------------------------------------------------------------------------
// Per block: (NT x 128-n tiles, hv, z). Wave w owns head hv*4+w.
// SWAPPED MFMA: acc[tt][m] = mfma(Wfrag, xfrag) -> D[oc][n]:
//   oc = ocb + tt*16 + l4*4 + r ; n = m*16 + l15.
// LN over 32 oc: in-lane (tt,r) adds + shfl_xor 16,32 across l4.
// KT/VT relayout is wave-private -> no barriers; b16 scatter writes.
#define LDC2 40
#define NT 2
__global__ __launch_bounds__(256, 2) void kv_scores(
    const ushort* __restrict__ xT, const ushort* __restrict__ Wkbf,
    const ushort* __restrict__ Wvbf, const float* __restrict__ bv,
    const float* __restrict__ gK, const float* __restrict__ bKp,
    const float* __restrict__ gV, const float* __restrict__ bVp,
    const float* __restrict__ PyKb, const float* __restrict__ PxKj,
    float* __restrict__ scores) {
  __shared__ ushort SQ[2][128 * 64];  // staged xT k-chunks (swizzled), dbuf
  __shared__ ushort KT[128 * LDC2];   // wave-private row bands
  __shared__ ushort VT[128 * LDC2];
  const int t = (int)threadIdx.x, lane = t & 63, w = t >> 6;
  const int l15 = lane & 15, l4 = lane >> 4;
  const int hv = (int)blockIdx.y, z = (int)blockIdx.z;
  const int bx = (int)blockIdx.x;
  const ushort* xb = xT + (size_t)z * 16384 * 256;
  const int ocb = hv * 128 + w * 32;
  const int h = hv * 4 + w;
  const int oc4 = ocb + l4 * 4;  // base oc of this lane's r-quad (tt adds 16)
  // per-oc params, r-indexed float4 (in-lane after the swap)
  const floatx4 bv4[2] = {*(const floatx4*)(bv + oc4),
                          *(const floatx4*)(bv + oc4 + 16)};
  const int hb = h * 32 + l4 * 4;
  const floatx4 gk4[2] = {*(const floatx4*)(gK + hb), *(const floatx4*)(gK + hb + 16)};
  const floatx4 ok4[2] = {*(const floatx4*)(bKp + hb), *(const floatx4*)(bKp + hb + 16)};
  const floatx4 gv4[2] = {*(const floatx4*)(gV + hb), *(const floatx4*)(gV + hb + 16)};
  const floatx4 ov4[2] = {*(const floatx4*)(bVp + hb), *(const floatx4*)(bVp + hb + 16)};
  const int srow = w * 32 + (lane >> 3);
  const int scol = (lane & 7) * 8;
  const int rsw = l15 & 7;

  auto issue = [&](int s) {
    const int n0s = (bx * NT + (s >> 2)) * 128;
    const int kcs = (s & 3) * 64;
    ushort* dst = &SQ[s & 1][w * 2048];
    const ushort* src = xb + (size_t)(n0s + srow) * 256 + kcs + scol;
#pragma unroll
    for (int j = 0; j < 4; ++j) gl_lds16(src + (size_t)j * 8 * 256, dst + j * 512);
  };
  issue(0);

  floatx4 sacc[2][2] = {};
  for (int nt = 0; nt < NT; ++nt) {
    const int i_nt = bx * NT + nt;
    floatx4 acck[2][8] = {};
    floatx4 accv[2][8] = {};
    for (int kc = 0; kc < 4; ++kc) {
      const int s = nt * 4 + kc;
      __syncthreads();  // drains stage s; protects buf (s+1)&1 overwrite
      // A-frags (W rows, L1/L2-hot); waiting on these precedes the stage issue
      bf16x8 Ak0[2], Ak1[2], Av0[2], Av1[2];
#pragma unroll
      for (int ci = 0; ci < 2; ++ci) {
        const int kb = (kc * 2 + ci) * 32 + l4 * 8;
        Ak0[ci] = frag(Wkbf + (ocb + l15) * 256 + kb);
        Ak1[ci] = frag(Wkbf + (ocb + 16 + l15) * 256 + kb);
        Av0[ci] = frag(Wvbf + (ocb + l15) * 256 + kb);
        Av1[ci] = frag(Wvbf + (ocb + 16 + l15) * 256 + kb);
      }
      if (s < NT * 4 - 1) issue(s + 1);  // drain lands at NEXT barrier
      const ushort* sq = &SQ[s & 1][0];
      __builtin_amdgcn_s_setprio(1);
#pragma unroll
      for (int ci = 0; ci < 2; ++ci) {
#pragma unroll
        for (int m = 0; m < 8; ++m) {
          const int off = (m * 16 + l15) * 64 + ((ci * 4 + l4) ^ rsw) * 8;
          const bf16x8 b = *(const bf16x8*)(sq + off);  // x-frag as B operand
          acck[0][m] = mfma16(Ak0[ci], b, acck[0][m]);
          acck[1][m] = mfma16(Ak1[ci], b, acck[1][m]);
          accv[0][m] = mfma16(Av0[ci], b, accv[0][m]);
          accv[1][m] = mfma16(Av1[ci], b, accv[1][m]);
        }
      }
      __builtin_amdgcn_s_setprio(0);
    }
    // pos-y table (per i-tile), r-indexed
    const floatx4 pyk[2] = {*(const floatx4*)(PyKb + i_nt * 256 + oc4),
                            *(const floatx4*)(PyKb + i_nt * 256 + oc4 + 16)};
    // LN + wave-private relayout + S-MFMA per 32-n quarter
#pragma unroll
    for (int q = 0; q < 4; ++q) {
#pragma unroll
      for (int mm = 0; mm < 2; ++mm) {
        const int m = q * 2 + mm;
        // K: add pos tables (pos-x per lane's n-col), then LN
        const floatx4 pxk0 = *(const floatx4*)(PxKj + (m * 16 + l15) * 256 + oc4);
        const floatx4 pxk1 = *(const floatx4*)(PxKj + (m * 16 + l15) * 256 + oc4 + 16);
        float s0 = 0.0f, q0 = 0.0f;
#pragma unroll
        for (int r = 0; r < 4; ++r) {
          acck[0][m][r] += pyk[0][r] + pxk0[r];
          acck[1][m][r] += pyk[1][r] + pxk1[r];
          const float v0 = acck[0][m][r], v1 = acck[1][m][r];
          s0 += v0 + v1;
          q0 += v0 * v0 + v1 * v1;
        }
        s0 += __shfl_xor(s0, 16); s0 += __shfl_xor(s0, 32);
        q0 += __shfl_xor(q0, 16); q0 += __shfl_xor(q0, 32);
        {
          const float mu = s0 * (1.0f / 32.0f);
          const float rstd = rsqrtf(q0 * (1.0f / 32.0f) - mu * mu + 1e-5f);
#pragma unroll
          for (int tt = 0; tt < 2; ++tt)
#pragma unroll
            for (int r = 0; r < 4; ++r)
              acck[tt][m][r] = (acck[tt][m][r] - mu) * rstd * gk4[tt][r] + ok4[tt][r];
        }
        // V: bias then LN
        float s1 = 0.0f, q1 = 0.0f;
#pragma unroll
        for (int r = 0; r < 4; ++r) {
          accv[0][m][r] += bv4[0][r];
          accv[1][m][r] += bv4[1][r];
          const float v0 = accv[0][m][r], v1 = accv[1][m][r];
          s1 += v0 + v1;
          q1 += v0 * v0 + v1 * v1;
        }
        s1 += __shfl_xor(s1, 16); s1 += __shfl_xor(s1, 32);
        q1 += __shfl_xor(q1, 16); q1 += __shfl_xor(q1, 32);
        {
          const float mu = s1 * (1.0f / 32.0f);
          const float rstd = rsqrtf(q1 * (1.0f / 32.0f) - mu * mu + 1e-5f);
#pragma unroll
          for (int tt = 0; tt < 2; ++tt)
#pragma unroll
            for (int r = 0; r < 4; ++r)
              accv[tt][m][r] = (accv[tt][m][r] - mu) * rstd * gv4[tt][r] + ov4[tt][r];
        }
        // wave-private relayout: KT[ch][ncol] b16 scatter (~2-way banks)
#pragma unroll
        for (int tt = 0; tt < 2; ++tt) {
          const int ch = w * 32 + tt * 16 + l4 * 4;
#pragma unroll
          for (int r = 0; r < 4; ++r) {
            KT[(ch + r) * LDC2 + mm * 16 + l15] = f2bf(acck[tt][m][r]);
            VT[(ch + r) * LDC2 + mm * 16 + l15] = f2bf(accv[tt][m][r]);
          }
        }
      }
      // S-MFMA on this quarter (in-wave lgkmcnt orders writes->reads)
      const int ko = l4 * 8;
      const bf16x8 ka0 = *(const bf16x8*)(KT + (w * 32 + l15) * LDC2 + ko);
      const bf16x8 ka1 = *(const bf16x8*)(KT + (w * 32 + 16 + l15) * LDC2 + ko);
      const bf16x8 vb0 = *(const bf16x8*)(VT + (w * 32 + l15) * LDC2 + ko);
      const bf16x8 vb1 = *(const bf16x8*)(VT + (w * 32 + 16 + l15) * LDC2 + ko);
      sacc[0][0] = mfma16(ka0, vb0, sacc[0][0]);
      sacc[0][1] = mfma16(ka0, vb1, sacc[0][1]);
      sacc[1][0] = mfma16(ka1, vb0, sacc[1][0]);
      sacc[1][1] = mfma16(ka1, vb1, sacc[1][1]);
    }
  }
#pragma unroll
  for (int di = 0; di < 2; ++di)
#pragma unroll
    for (int ej = 0; ej < 2; ++ej)
#pragma unroll
      for (int r = 0; r < 4; ++r) {
        const int d = di * 16 + l4 * 4 + r;
        const int e = ej * 16 + l15;
        atomicAdd(scores + ((size_t)(z * 8 + h) * 32 + d) * 32 + e, sacc[di][ej][r]);
      }
}

// ---------------------------------------------------------------------------
// W2bf/W2f[z][he][r] = sum_d Wq[hd][r] S'[d][e] / n ; b2 = bq-fold / n.
__global__ __launch_bounds__(256) void w2_kernel(
    const float* __restrict__ Wq, const float* __restrict__ bq,
    const float* __restrict__ scores, ushort* __restrict__ W2bf,
    float* __restrict__ W2f, float* __restrict__ b2) {
  const int z = (int)blockIdx.y;
  const int row = (int)blockIdx.x;
  const int t = (int)threadIdx.x;
  const float inv_n = 1.0f / 16384.0f;
  const float* sc = scores + (size_t)z * 8192;
  if (row < 256) {
    const int h = row >> 5, e = row & 31;
    float s = 0.0f;
#pragma unroll
    for (int d = 0; d < 32; ++d)
      s += Wq[(h * 32 + d) * 256 + t] * sc[(h * 32 + d) * 32 + e];
    const float v = s * inv_n;
    W2bf[(size_t)z * 65536 + row * 256 + t] = f2bf(v);
    W2f[(size_t)z * 65536 + row * 256 + t] = v;
  } else {
    const int h = t >> 5, e = t & 31;
    float s = 0.0f;
#pragma unroll
    for (int d = 0; d < 32; ++d)
      s += bq[h * 32 + d] * sc[(h * 32 + d) * 32 + e];
    b2[z * 256 + t] = s * inv_n;
  }
}

// ---------------------------------------------------------------------------
// out = LN(2*(x W2^T + Py2[i] + Px2[j])) stored NCHW (b2 folded into Py2).
// xT is XOR-swizzled: sub-chunk lc read at lc ^ (row&7).
__global__ __launch_bounds__(256, 2) void out_kernel(
    const ushort* __restrict__ xT, const ushort* __restrict__ W2bf,
    const float* __restrict__ Py2b, const float* __restrict__ Px2T,
    const float* __restrict__ g_ln, const float* __restrict__ b_ln,
    float* __restrict__ out, int b0) {
  const int t = (int)threadIdx.x, lane = t & 63, w = t >> 6;
  const int l15 = lane & 15, l4 = lane >> 4;
  const int z = (int)blockIdx.y, b = b0 + z;
  const int bx = (int)blockIdx.x;
  const int n0 = bx * 64;
  const ushort* xb = xT + (size_t)z * 16384 * 256;
  const ushort* W2b = W2bf + (size_t)z * 65536;
  const float* py = Py2b + ((size_t)z * 128 + (bx >> 1)) * 256;
  const float* pxT = Px2T + (size_t)z * 32768;
  const int jbase = (bx & 1) * 64 + w * 16 + l4 * 4;
  const int row = n0 + w * 16 + l15;
  const int rsw = l15 & 7;
  floatx4 acc[16] = {};
#pragma unroll
  for (int c = 0; c < 8; ++c) {
    const int kb = c * 32 + l4 * 8;
    const int off = (c >> 1) * 64 + ((((c & 1) * 4 + l4) ^ rsw)) * 8;
    const bf16x8 a = frag(xb + (size_t)row * 256 + off);
#pragma unroll
    for (int tt = 0; tt < 16; ++tt) {
      const bf16x8 bb = frag(W2b + (tt * 16 + l15) * 256 + kb);
      acc[tt] = mfma16(a, bb, acc[tt]);
    }
  }
  // + pos/bias tables, double, LN over 256 channels, NCHW store
#pragma unroll
  for (int tt = 0; tt < 16; ++tt) {
    const int c = tt * 16 + l15;
    const float pyv = py[c];
    const float4 px = *(const float4*)(pxT + c * 128 + jbase);
    const float pxa[4] = {px.x, px.y, px.z, px.w};
#pragma unroll
    for (int r = 0; r < 4; ++r) acc[tt][r] = 2.0f * (acc[tt][r] + pyv + pxa[r]);
  }
  float mean[4], rstd[4];
#pragma unroll
  for (int r = 0; r < 4; ++r) {
    float s = 0.0f, q = 0.0f;
#pragma unroll
    for (int tt = 0; tt < 16; ++tt) {
      const float v = acc[tt][r];
      s += v;
      q += v * v;
    }
#pragma unroll
    for (int msk = 1; msk < 16; msk <<= 1) {
      s += __shfl_xor(s, msk);
      q += __shfl_xor(q, msk);
    }
    const float mu = s * (1.0f / 256.0f);
    mean[r] = mu;
    rstd[r] = rsqrtf(q * (1.0f / 256.0f) - mu * mu + 1e-5f);
  }
#pragma unroll
  for (int tt = 0; tt < 16; ++tt) {
    const int c = tt * 16 + l15;
    const float g = g_ln[c], be = b_ln[c];
    float4 o;
    o.x = (acc[tt][0] - mean[0]) * rstd[0] * g + be;
    o.y = (acc[tt][1] - mean[1]) * rstd[1] * g + be;
    o.z = (acc[tt][2] - mean[2]) * rstd[2] * g + be;
    o.w = (acc[tt][3] - mean[3]) * rstd[3] * g + be;
    *(float4*)(out + (size_t)(b * 256 + c) * 16384 + n0 + w * 16 + l4 * 4) = o;
  }
}

// ---------------------------------------------------------------------------
extern "C" void kernel_launch(void* const* d_in, const int* in_sizes, int n_in,
                              void* d_out, int out_size, void* d_ws, size_t ws_size,
                              hipStream_t stream) {
  (void)in_sizes; (void)n_in; (void)out_size;
  const float* x   = (const float*)d_in[0];
  const float* Wq  = (const float*)d_in[1];
  const float* bq  = (const float*)d_in[2];
  const float* Wk  = (const float*)d_in[3];
  const float* bk  = (const float*)d_in[4];
  const float* Wv  = (const float*)d_in[5];
  const float* bv  = (const float*)d_in[6];
  const float* gK  = (const float*)d_in[7];
  const float* bK  = (const float*)d_in[8];
  const float* gV  = (const float*)d_in[9];
  const float* bV  = (const float*)d_in[10];
  const float* gln = (const float*)d_in[11];
  const float* bln = (const float*)d_in[12];
  float* out = (float*)d_out;

  // Per-batch: xT 8MB + W2bf 128K + W2f 256K + scores 32K + b2 1K + Py2 128K
  //            + Px2 128K. Shared: Wk/Wv bf 256K + K-tables 256K.
  const size_t PB = 16384ULL * 256 * 2;
  const size_t PERZ = PB + 131072 + 262144 + 32768 + 1024 + 131072 + 131072;
  const size_t SHARED = 262144 + 262144;
  int g = 8;
  while (g > 1 && ws_size < (size_t)g * PERZ + SHARED) g >>= 1;
  // g=1 needs 9,602,048 B <= proven-safe 18,096,128 B.

  char* p = (char*)d_ws;
  ushort* xT    = (ushort*)p; p += (size_t)g * PB;
  ushort* Wkbf  = (ushort*)p; p += 131072;
  ushort* Wvbf  = (ushort*)p; p += 131072;
  float*  PyKb  = (float*)p;  p += 131072;
  float*  PxKj  = (float*)p;  p += 131072;
  ushort* W2bf  = (ushort*)p; p += (size_t)g * 131072;
  float*  W2f   = (float*)p;  p += (size_t)g * 262144;
  float*  Py2b  = (float*)p;  p += (size_t)g * 131072;
  float*  Px2T  = (float*)p;  p += (size_t)g * 131072;
  float*  scores = (float*)p; p += (size_t)g * 32768;
  float*  b2    = (float*)p;

  prep_w<<<dim3(64), 256, 0, stream>>>(Wk, Wv, Wkbf, Wvbf);
  poswk<<<dim3(128), 256, 0, stream>>>(Wk, bk, PyKb, PxKj);
  for (int b0 = 0; b0 < 8; b0 += g) {
    hipMemsetAsync(scores, 0, (size_t)g * 32768, stream);
    prep_qx<<<dim3(256, g), 256, 0, stream>>>(x, xT, b0);
    kv_scores<<<dim3(128 / NT, 2, g), 256, 0, stream>>>(xT, Wkbf, Wvbf, bv, gK, bK,
                                                        gV, bV, PyKb, PxKj, scores);
    w2_kernel<<<dim3(257, g), 256, 0, stream>>>(Wq, bq, scores, W2bf, W2f, b2);
    posw2<<<dim3(128, g), 256, 0, stream>>>(W2f, b2, Py2b, Px2T);
    out_kernel<<<dim3(256, g), 256, 0, stream>>>(xT, W2bf, Py2b, Px2T, gln, bln,
                                                 out, b0);
  }
}

// Round 8
// 586.928 us; speedup vs baseline: 1.1036x; 1.1036x over previous
//
#include <hip/hip_runtime.h>

// SelfAttention (Galerkin linear attention), round 7 (third resubmit — R5, R6,
// R7 benches were all GPUAcquisitionTimeout, no signal).
// Algebra: qk_in = x + pos ; K = qk_in Wk^T + bk ; V = x Wv^T + bv
//          (per-head LN on K,V) ; S'_h = K_h^T V_h / n
//          W2[he][r] = sum_d Wq[hd][r] S'[d][e] ; b2[he] = sum_d bq[hd] S'[d][e]
//          out = LN(2*(qk_in W2^T + b2)) stored NCHW.
// Kept from R5/R6: separable pos -> f32 tables (PyK[i][oc], PxK[j][oc],
//   Py2[i][e], Px2[e][j]); only xT=bf16(x) staged (XOR-swizzled for
//   global_load_lds + conflict-free ds_read_b128); swapped MFMA (A=W,B=x ->
//   D[oc][n], lane-local LN); wave-private KT/VT relayout (no barriers).
// R7: counters showed kv_scores is ATOMIC-TRAFFIC bound:
//   WRITE_SIZE == 296 MiB == 4.2M atomicAdds x 64B (device-scope atomics
//   write through the non-coherent per-XCD L2s); hbm_bytes 635 MB vs ~100
//   ideal; dur == bytes/BW. Fix:
//   1) split-K partials: each block stores its 32x32xf32 per-head tile with
//      plain coalesced stores; new reduce_scores kernel sums 32 partials per
//      (z,h). ~400 MB atomic RMW -> 16 MB. scores memset dropped.
//   2) 8-wave blocks (wave w = head w): xT fetched ONCE (67 MB, was 2x).
//      NT=4 -> grid (32,g)=256 blocks, LDS 72 KB.
//   3) W2f (f32 copy) dropped; posw2 reads bf16 W2 (same quantization the
//      out-GEMM uses). Adaptive g: g=8 needs 79.4 MB else halves.

typedef float floatx4 __attribute__((ext_vector_type(4)));
typedef __bf16 bf16x8 __attribute__((ext_vector_type(8)));
typedef unsigned short ushortx8 __attribute__((ext_vector_type(8)));
typedef unsigned short ushort;

static __device__ __forceinline__ ushort f2bf(float f) {
  unsigned int u = __builtin_bit_cast(unsigned int, f);
  u += 0x7FFFu + ((u >> 16) & 1u);  // RNE
  return (ushort)(u >> 16);
}
static __device__ __forceinline__ float bf2f(ushort u) {
  unsigned int x = ((unsigned int)u) << 16;
  return __builtin_bit_cast(float, x);
}
static __device__ __forceinline__ floatx4 mfma16(bf16x8 a, bf16x8 b, floatx4 c) {
  return __builtin_amdgcn_mfma_f32_16x16x32_bf16(a, b, c, 0, 0, 0);
}
static __device__ __forceinline__ bf16x8 frag(const ushort* p) {
  return *(const bf16x8*)p;  // 16-B aligned by construction -> dwordx4
}
typedef __attribute__((address_space(3))) unsigned int as3_u32;
typedef __attribute__((address_space(1))) const unsigned int as1_u32;
static __device__ __forceinline__ void gl_lds16(const ushort* g, ushort* l) {
  __builtin_amdgcn_global_load_lds((as1_u32*)g, (as3_u32*)l, 16, 0, 0);
}

// ---------------------------------------------------------------------------
// Wk, Wv fp32 -> bf16 (plain [oc][256]).
__global__ __launch_bounds__(256) void prep_w(const float* __restrict__ Wk,
                                              const float* __restrict__ Wv,
                                              ushort* __restrict__ Wkbf,
                                              ushort* __restrict__ Wvbf) {
  const int i = (int)blockIdx.x * 256 + (int)threadIdx.x;
  float4 a = ((const float4*)Wk)[i];
  float4 b = ((const float4*)Wv)[i];
  ushort4 ua = {f2bf(a.x), f2bf(a.y), f2bf(a.z), f2bf(a.w)};
  ushort4 ub = {f2bf(b.x), f2bf(b.y), f2bf(b.z), f2bf(b.w)};
  ((ushort4*)Wkbf)[i] = ua;
  ((ushort4*)Wvbf)[i] = ub;
}

// ---------------------------------------------------------------------------
// Pos tables for K: PyKb[i][oc] = bk[oc] + sum_{kk<128} pe(i,kk)*Wk[oc][kk]
//                   PxKj[j][oc] =          sum_{kk<128} pe(j,kk)*Wk[oc][128+kk]
__global__ __launch_bounds__(256) void poswk(const float* __restrict__ Wk,
                                             const float* __restrict__ bk,
                                             float* __restrict__ PyKb,
                                             float* __restrict__ PxKj) {
  __shared__ float pe[128];
  const int ii = (int)blockIdx.x, t = (int)threadIdx.x;
  if (t < 128) {
    const float coord = (float)(ii + 1) * (6.283185307179586f / (128.0f + 1e-6f));
    const float inv = exp2f(-13.287712379549449f * (float)(t >> 1) * (1.0f / 64.0f));
    const float arg = coord * inv;
    pe[t] = (t & 1) ? cosf(arg) : sinf(arg);
  }
  __syncthreads();
  const float* wrow = Wk + (size_t)t * 256;
  float py = bk[t], px = 0.0f;
#pragma unroll 8
  for (int kk = 0; kk < 128; ++kk) {
    py += pe[kk] * wrow[kk];
    px += pe[kk] * wrow[128 + kk];
  }
  PyKb[ii * 256 + t] = py;
  PxKj[ii * 256 + t] = px;  // [j][oc]
}

// ---------------------------------------------------------------------------
// Pos tables for W2 (per z), from bf16 W2 (same quantization the GEMM uses):
//   Py2b[z][i][e] = b2[z][e] + pos_y(i) @ W2[z][e][:128]
//   Px2T[z][e][j] =            pos_x(j) @ W2[z][e][128:]
__global__ __launch_bounds__(256) void posw2(const ushort* __restrict__ W2bf,
                                             const float* __restrict__ b2,
                                             float* __restrict__ Py2b,
                                             float* __restrict__ Px2T) {
  __shared__ float pe[128];
  const int ii = (int)blockIdx.x, z = (int)blockIdx.y, t = (int)threadIdx.x;
  if (t < 128) {
    const float coord = (float)(ii + 1) * (6.283185307179586f / (128.0f + 1e-6f));
    const float inv = exp2f(-13.287712379549449f * (float)(t >> 1) * (1.0f / 64.0f));
    const float arg = coord * inv;
    pe[t] = (t & 1) ? cosf(arg) : sinf(arg);
  }
  __syncthreads();
  const ushort* wrow = W2bf + (size_t)z * 65536 + (size_t)t * 256;
  float py = b2[z * 256 + t], px = 0.0f;
#pragma unroll 8
  for (int kk = 0; kk < 128; ++kk) {
    py += pe[kk] * bf2f(wrow[kk]);
    px += pe[kk] * bf2f(wrow[128 + kk]);
  }
  Py2b[((size_t)z * 128 + ii) * 256 + t] = py;
  Px2T[(size_t)z * 32768 + t * 128 + ii] = px;
}

// ---------------------------------------------------------------------------
// For batch b0+z: xT[z][n][k] = bf16(x). SWIZZLED store: 16B sub-chunk p
// stored at p ^ (n&7) within each 64-k group.
__global__ __launch_bounds__(256) void prep_qx(const float* __restrict__ x,
                                               ushort* __restrict__ xT, int b0) {
  __shared__ float tile[64 * 68];
  const int t = (int)threadIdx.x;
  const int z = (int)blockIdx.y;
  const int b = b0 + z;
  const int n0 = (int)blockIdx.x * 64;
  const float* xb = x + (size_t)b * 256 * 16384;
  ushort* xtb = xT + (size_t)z * 16384 * 256;
  for (int kc = 0; kc < 4; ++kc) {
    if (kc) __syncthreads();
    const int nn = (t & 15) * 4;
    const int r0 = t >> 4;
#pragma unroll
    for (int it = 0; it < 4; ++it) {
      const int k = r0 + it * 16;
      const float4 v = *(const float4*)(xb + (size_t)(kc * 64 + k) * 16384 + n0 + nn);
      tile[(nn + 0) * 68 + k] = v.x;
      tile[(nn + 1) * 68 + k] = v.y;
      tile[(nn + 2) * 68 + k] = v.z;
      tile[(nn + 3) * 68 + k] = v.w;
    }
    __syncthreads();
#pragma unroll
    for (int it = 0; it < 2; ++it) {
      const int P = t + it * 256;
      const int r = P >> 3;  // n row 0..63
      const int p = P & 7;   // k chunk of 8
      const int n = n0 + r;
      ushortx8 ux;
#pragma unroll
      for (int e = 0; e < 8; ++e) ux[e] = f2bf(tile[r * 68 + p * 8 + e]);
      const int sw = (p ^ (r & 7)) * 8;
      *(ushortx8*)(xtb + (size_t)n * 256 + kc * 64 + sw) = ux;
    }
  }
}

// ---------------------------------------------------------------------------
// Per block: (NT x 128-n tiles, z); 8 waves, wave w = head w. xT read ONCE.
// SWAPPED MFMA: acc[tt][m] = mfma(Wfrag, xfrag) -> D[oc][n]:
//   oc = w*32 + tt*16 + l4*4 + r ; n = m*16 + l15.
// LN over 32 oc: in-lane (tt,r) adds + shfl_xor 16,32 across l4.
// KT/VT relayout wave-private (rows w*32..+32) -> no barriers.
// Output: plain-stored f32 partial tile per (z,h,bx) -> reduce_scores.
#define LDC2 40
#define NT 4
__global__ __launch_bounds__(512, 2) void kv_scores(
    const ushort* __restrict__ xT, const ushort* __restrict__ Wkbf,
    const ushort* __restrict__ Wvbf, const float* __restrict__ bv,
    const float* __restrict__ gK, const float* __restrict__ bKp,
    const float* __restrict__ gV, const float* __restrict__ bVp,
    const float* __restrict__ PyKb, const float* __restrict__ PxKj,
    float* __restrict__ partials) {
  __shared__ ushort SQ[2][128 * 64];  // staged xT k-chunks (swizzled), dbuf
  __shared__ ushort KT[256 * LDC2];   // wave-private 32-row bands
  __shared__ ushort VT[256 * LDC2];
  const int t = (int)threadIdx.x, lane = t & 63, w = t >> 6;  // w = head 0..7
  const int l15 = lane & 15, l4 = lane >> 4;
  const int z = (int)blockIdx.y;
  const int bx = (int)blockIdx.x;
  const ushort* xb = xT + (size_t)z * 16384 * 256;
  const int ocb = w * 32;
  const int h = w;
  const int oc4 = ocb + l4 * 4;  // base oc of this lane's r-quad (tt adds 16)
  // per-oc params, r-indexed float4 (in-lane after the swap)
  const floatx4 bv4[2] = {*(const floatx4*)(bv + oc4),
                          *(const floatx4*)(bv + oc4 + 16)};
  const int hb = h * 32 + l4 * 4;
  const floatx4 gk4[2] = {*(const floatx4*)(gK + hb), *(const floatx4*)(gK + hb + 16)};
  const floatx4 ok4[2] = {*(const floatx4*)(bKp + hb), *(const floatx4*)(bKp + hb + 16)};
  const floatx4 gv4[2] = {*(const floatx4*)(gV + hb), *(const floatx4*)(gV + hb + 16)};
  const floatx4 ov4[2] = {*(const floatx4*)(bVp + hb), *(const floatx4*)(bVp + hb + 16)};
  // staging: wave w copies rows [w*16, w*16+16), 8 rows per issue, 2 issues
  const int srow = w * 16 + (lane >> 3);
  const int scol = (lane & 7) * 8;
  const int rsw = l15 & 7;

  auto issue = [&](int s) {
    const int n0s = (bx * NT + (s >> 2)) * 128;
    const int kcs = (s & 3) * 64;
    ushort* dst = &SQ[s & 1][w * 1024];
    const ushort* src = xb + (size_t)(n0s + srow) * 256 + kcs + scol;
#pragma unroll
    for (int j = 0; j < 2; ++j) gl_lds16(src + (size_t)j * 8 * 256, dst + j * 512);
  };
  issue(0);

  floatx4 sacc[2][2] = {};
  for (int nt = 0; nt < NT; ++nt) {
    const int i_nt = bx * NT + nt;
    floatx4 acck[2][8] = {};
    floatx4 accv[2][8] = {};
    for (int kc = 0; kc < 4; ++kc) {
      const int s = nt * 4 + kc;
      __syncthreads();  // drains stage s; protects buf (s+1)&1 overwrite
      // A-frags (W rows, L1/L2-hot)
      bf16x8 Ak0[2], Ak1[2], Av0[2], Av1[2];
#pragma unroll
      for (int ci = 0; ci < 2; ++ci) {
        const int kb = (kc * 2 + ci) * 32 + l4 * 8;
        Ak0[ci] = frag(Wkbf + (ocb + l15) * 256 + kb);
        Ak1[ci] = frag(Wkbf + (ocb + 16 + l15) * 256 + kb);
        Av0[ci] = frag(Wvbf + (ocb + l15) * 256 + kb);
        Av1[ci] = frag(Wvbf + (ocb + 16 + l15) * 256 + kb);
      }
      if (s < NT * 4 - 1) issue(s + 1);  // drain lands at NEXT barrier
      const ushort* sq = &SQ[s & 1][0];
      __builtin_amdgcn_s_setprio(1);
#pragma unroll
      for (int ci = 0; ci < 2; ++ci) {
#pragma unroll
        for (int m = 0; m < 8; ++m) {
          const int off = (m * 16 + l15) * 64 + ((ci * 4 + l4) ^ rsw) * 8;
          const bf16x8 b = *(const bf16x8*)(sq + off);  // x-frag as B operand
          acck[0][m] = mfma16(Ak0[ci], b, acck[0][m]);
          acck[1][m] = mfma16(Ak1[ci], b, acck[1][m]);
          accv[0][m] = mfma16(Av0[ci], b, accv[0][m]);
          accv[1][m] = mfma16(Av1[ci], b, accv[1][m]);
        }
      }
      __builtin_amdgcn_s_setprio(0);
    }
    // pos-y table (per i-tile), r-indexed
    const floatx4 pyk[2] = {*(const floatx4*)(PyKb + i_nt * 256 + oc4),
                            *(const floatx4*)(PyKb + i_nt * 256 + oc4 + 16)};
    // LN + wave-private relayout + S-MFMA per 32-n quarter
#pragma unroll
    for (int q = 0; q < 4; ++q) {
#pragma unroll
      for (int mm = 0; mm < 2; ++mm) {
        const int m = q * 2 + mm;
        // K: add pos tables (pos-x per lane's n-col), then LN
        const floatx4 pxk0 = *(const floatx4*)(PxKj + (m * 16 + l15) * 256 + oc4);
        const floatx4 pxk1 = *(const floatx4*)(PxKj + (m * 16 + l15) * 256 + oc4 + 16);
        float s0 = 0.0f, q0 = 0.0f;
#pragma unroll
        for (int r = 0; r < 4; ++r) {
          acck[0][m][r] += pyk[0][r] + pxk0[r];
          acck[1][m][r] += pyk[1][r] + pxk1[r];
          const float v0 = acck[0][m][r], v1 = acck[1][m][r];
          s0 += v0 + v1;
          q0 += v0 * v0 + v1 * v1;
        }
        s0 += __shfl_xor(s0, 16); s0 += __shfl_xor(s0, 32);
        q0 += __shfl_xor(q0, 16); q0 += __shfl_xor(q0, 32);
        {
          const float mu = s0 * (1.0f / 32.0f);
          const float rstd = rsqrtf(q0 * (1.0f / 32.0f) - mu * mu + 1e-5f);
#pragma unroll
          for (int tt = 0; tt < 2; ++tt)
#pragma unroll
            for (int r = 0; r < 4; ++r)
              acck[tt][m][r] = (acck[tt][m][r] - mu) * rstd * gk4[tt][r] + ok4[tt][r];
        }
        // V: bias then LN
        float s1 = 0.0f, q1 = 0.0f;
#pragma unroll
        for (int r = 0; r < 4; ++r) {
          accv[0][m][r] += bv4[0][r];
          accv[1][m][r] += bv4[1][r];
          const float v0 = accv[0][m][r], v1 = accv[1][m][r];
          s1 += v0 + v1;
          q1 += v0 * v0 + v1 * v1;
        }
        s1 += __shfl_xor(s1, 16); s1 += __shfl_xor(s1, 32);
        q1 += __shfl_xor(q1, 16); q1 += __shfl_xor(q1, 32);
        {
          const float mu = s1 * (1.0f / 32.0f);
          const float rstd = rsqrtf(q1 * (1.0f / 32.0f) - mu * mu + 1e-5f);
#pragma unroll
          for (int tt = 0; tt < 2; ++tt)
#pragma unroll
            for (int r = 0; r < 4; ++r)
              accv[tt][m][r] = (accv[tt][m][r] - mu) * rstd * gv4[tt][r] + ov4[tt][r];
        }
        // wave-private relayout: KT[ch][ncol] b16 scatter (~2-way banks)
#pragma unroll
        for (int tt = 0; tt < 2; ++tt) {
          const int ch = w * 32 + tt * 16 + l4 * 4;
#pragma unroll
          for (int r = 0; r < 4; ++r) {
            KT[(ch + r) * LDC2 + mm * 16 + l15] = f2bf(acck[tt][m][r]);
            VT[(ch + r) * LDC2 + mm * 16 + l15] = f2bf(accv[tt][m][r]);
          }
        }
      }
      // S-MFMA on this quarter (in-wave lgkmcnt orders writes->reads)
      const int ko = l4 * 8;
      const bf16x8 ka0 = *(const bf16x8*)(KT + (w * 32 + l15) * LDC2 + ko);
      const bf16x8 ka1 = *(const bf16x8*)(KT + (w * 32 + 16 + l15) * LDC2 + ko);
      const bf16x8 vb0 = *(const bf16x8*)(VT + (w * 32 + l15) * LDC2 + ko);
      const bf16x8 vb1 = *(const bf16x8*)(VT + (w * 32 + 16 + l15) * LDC2 + ko);
      sacc[0][0] = mfma16(ka0, vb0, sacc[0][0]);
      sacc[0][1] = mfma16(ka0, vb1, sacc[0][1]);
      sacc[1][0] = mfma16(ka1, vb0, sacc[1][0]);
      sacc[1][1] = mfma16(ka1, vb1, sacc[1][1]);
    }
  }
  // plain coalesced partial store (no atomics)
  float* pp = partials + (((size_t)z * 8 + h) * 32 + bx) * 1024;
#pragma unroll
  for (int di = 0; di < 2; ++di)
#pragma unroll
    for (int ej = 0; ej < 2; ++ej)
#pragma unroll
      for (int r = 0; r < 4; ++r)
        pp[(di * 16 + l4 * 4 + r) * 32 + ej * 16 + l15] = sacc[di][ej][r];
}

// ---------------------------------------------------------------------------
// scores[z][h][d][e] = sum_bx partials[z][h][bx][d][e]  (raw sum; w2 scales)
__global__ __launch_bounds__(256) void reduce_scores(
    const float* __restrict__ partials, float* __restrict__ scores) {
  const int h = (int)blockIdx.x, z = (int)blockIdx.y, t = (int)threadIdx.x;
  const float* pb = partials + ((size_t)(z * 8 + h) * 32) * 1024 + t * 4;
  float4 s = {0.0f, 0.0f, 0.0f, 0.0f};
#pragma unroll 8
  for (int bx = 0; bx < 32; ++bx) {
    const float4 v = *(const float4*)(pb + bx * 1024);
    s.x += v.x; s.y += v.y; s.z += v.z; s.w += v.w;
  }
  *(float4*)(scores + (size_t)(z * 8 + h) * 1024 + t * 4) = s;
}

// ---------------------------------------------------------------------------
// W2bf[z][he][r] = sum_d Wq[hd][r] S'[d][e] / n ; b2 = bq-fold / n.
__global__ __launch_bounds__(256) void w2_kernel(
    const float* __restrict__ Wq, const float* __restrict__ bq,
    const float* __restrict__ scores, ushort* __restrict__ W2bf,
    float* __restrict__ b2) {
  const int z = (int)blockIdx.y;
  const int row = (int)blockIdx.x;
  const int t = (int)threadIdx.x;
  const float inv_n = 1.0f / 16384.0f;
  const float* sc = scores + (size_t)z * 8192;
  if (row < 256) {
    const int h = row >> 5, e = row & 31;
    float s = 0.0f;
#pragma unroll
    for (int d = 0; d < 32; ++d)
      s += Wq[(h * 32 + d) * 256 + t] * sc[(h * 32 + d) * 32 + e];
    W2bf[(size_t)z * 65536 + row * 256 + t] = f2bf(s * inv_n);
  } else {
    const int h = t >> 5, e = t & 31;
    float s = 0.0f;
#pragma unroll
    for (int d = 0; d < 32; ++d)
      s += bq[h * 32 + d] * sc[(h * 32 + d) * 32 + e];
    b2[z * 256 + t] = s * inv_n;
  }
}

// ---------------------------------------------------------------------------
// out = LN(2*(x W2^T + Py2[i] + Px2[j])) stored NCHW (b2 folded into Py2).
// xT is XOR-swizzled: sub-chunk lc read at lc ^ (row&7).
__global__ __launch_bounds__(256, 2) void out_kernel(
    const ushort* __restrict__ xT, const ushort* __restrict__ W2bf,
    const float* __restrict__ Py2b, const float* __restrict__ Px2T,
    const float* __restrict__ g_ln, const float* __restrict__ b_ln,
    float* __restrict__ out, int b0) {
  const int t = (int)threadIdx.x, lane = t & 63, w = t >> 6;
  const int l15 = lane & 15, l4 = lane >> 4;
  const int z = (int)blockIdx.y, b = b0 + z;
  const int bx = (int)blockIdx.x;
  const int n0 = bx * 64;
  const ushort* xb = xT + (size_t)z * 16384 * 256;
  const ushort* W2b = W2bf + (size_t)z * 65536;
  const float* py = Py2b + ((size_t)z * 128 + (bx >> 1)) * 256;
  const float* pxT = Px2T + (size_t)z * 32768;
  const int jbase = (bx & 1) * 64 + w * 16 + l4 * 4;
  const int row = n0 + w * 16 + l15;
  const int rsw = l15 & 7;
  floatx4 acc[16] = {};
#pragma unroll
  for (int c = 0; c < 8; ++c) {
    const int kb = c * 32 + l4 * 8;
    const int off = (c >> 1) * 64 + ((((c & 1) * 4 + l4) ^ rsw)) * 8;
    const bf16x8 a = frag(xb + (size_t)row * 256 + off);
#pragma unroll
    for (int tt = 0; tt < 16; ++tt) {
      const bf16x8 bb = frag(W2b + (tt * 16 + l15) * 256 + kb);
      acc[tt] = mfma16(a, bb, acc[tt]);
    }
  }
  // + pos/bias tables, double, LN over 256 channels, NCHW store
#pragma unroll
  for (int tt = 0; tt < 16; ++tt) {
    const int c = tt * 16 + l15;
    const float pyv = py[c];
    const float4 px = *(const float4*)(pxT + c * 128 + jbase);
    const float pxa[4] = {px.x, px.y, px.z, px.w};
#pragma unroll
    for (int r = 0; r < 4; ++r) acc[tt][r] = 2.0f * (acc[tt][r] + pyv + pxa[r]);
  }
  float mean[4], rstd[4];
#pragma unroll
  for (int r = 0; r < 4; ++r) {
    float s = 0.0f, q = 0.0f;
#pragma unroll
    for (int tt = 0; tt < 16; ++tt) {
      const float v = acc[tt][r];
      s += v;
      q += v * v;
    }
#pragma unroll
    for (int msk = 1; msk < 16; msk <<= 1) {
      s += __shfl_xor(s, msk);
      q += __shfl_xor(q, msk);
    }
    const float mu = s * (1.0f / 256.0f);
    mean[r] = mu;
    rstd[r] = rsqrtf(q * (1.0f / 256.0f) - mu * mu + 1e-5f);
  }
#pragma unroll
  for (int tt = 0; tt < 16; ++tt) {
    const int c = tt * 16 + l15;
    const float g = g_ln[c], be = b_ln[c];
    float4 o;
    o.x = (acc[tt][0] - mean[0]) * rstd[0] * g + be;
    o.y = (acc[tt][1] - mean[1]) * rstd[1] * g + be;
    o.z = (acc[tt][2] - mean[2]) * rstd[2] * g + be;
    o.w = (acc[tt][3] - mean[3]) * rstd[3] * g + be;
    *(float4*)(out + (size_t)(b * 256 + c) * 16384 + n0 + w * 16 + l4 * 4) = o;
  }
}

// ---------------------------------------------------------------------------
extern "C" void kernel_launch(void* const* d_in, const int* in_sizes, int n_in,
                              void* d_out, int out_size, void* d_ws, size_t ws_size,
                              hipStream_t stream) {
  (void)in_sizes; (void)n_in; (void)out_size;
  const float* x   = (const float*)d_in[0];
  const float* Wq  = (const float*)d_in[1];
  const float* bq  = (const float*)d_in[2];
  const float* Wk  = (const float*)d_in[3];
  const float* bk  = (const float*)d_in[4];
  const float* Wv  = (const float*)d_in[5];
  const float* bv  = (const float*)d_in[6];
  const float* gK  = (const float*)d_in[7];
  const float* bK  = (const float*)d_in[8];
  const float* gV  = (const float*)d_in[9];
  const float* bV  = (const float*)d_in[10];
  const float* gln = (const float*)d_in[11];
  const float* bln = (const float*)d_in[12];
  float* out = (float*)d_out;

  // Per-batch: xT 8MB + W2bf 128K + Py2 128K + Px2 128K + partials 1MB
  //            + scores 32K + b2 1K = 9,864,192 B.
  // Shared: Wk/Wv bf 256K + K-tables 256K. g=8 -> 79.4 MB; halves if needed.
  const size_t PB = 16384ULL * 256 * 2;
  const size_t PERZ = PB + 131072 + 131072 + 131072 + 1048576 + 32768 + 1024;
  const size_t SHARED = 262144 + 262144;
  int g = 8;
  while (g > 1 && ws_size < (size_t)g * PERZ + SHARED) g >>= 1;
  // g=1 needs 10,388,480 B <= proven-safe 18,096,128 B.

  char* p = (char*)d_ws;
  ushort* xT    = (ushort*)p; p += (size_t)g * PB;
  ushort* Wkbf  = (ushort*)p; p += 131072;
  ushort* Wvbf  = (ushort*)p; p += 131072;
  float*  PyKb  = (float*)p;  p += 131072;
  float*  PxKj  = (float*)p;  p += 131072;
  ushort* W2bf  = (ushort*)p; p += (size_t)g * 131072;
  float*  Py2b  = (float*)p;  p += (size_t)g * 131072;
  float*  Px2T  = (float*)p;  p += (size_t)g * 131072;
  float*  partials = (float*)p; p += (size_t)g * 1048576;
  float*  scores = (float*)p; p += (size_t)g * 32768;
  float*  b2    = (float*)p;

  prep_w<<<dim3(64), 256, 0, stream>>>(Wk, Wv, Wkbf, Wvbf);
  poswk<<<dim3(128), 256, 0, stream>>>(Wk, bk, PyKb, PxKj);
  for (int b0 = 0; b0 < 8; b0 += g) {
    prep_qx<<<dim3(256, g), 256, 0, stream>>>(x, xT, b0);
    kv_scores<<<dim3(32, g), 512, 0, stream>>>(xT, Wkbf, Wvbf, bv, gK, bK,
                                               gV, bV, PyKb, PxKj, partials);
    reduce_scores<<<dim3(8, g), 256, 0, stream>>>(partials, scores);
    w2_kernel<<<dim3(257, g), 256, 0, stream>>>(Wq, bq, scores, W2bf, b2);
    posw2<<<dim3(128, g), 256, 0, stream>>>(W2bf, b2, Py2b, Px2T);
    out_kernel<<<dim3(256, g), 256, 0, stream>>>(xT, W2bf, Py2b, Px2T, gln, bln,
                                                 out, b0);
  }
}

// Round 11
// 503.239 us; speedup vs baseline: 1.2872x; 1.1663x over previous
//
#include <hip/hip_runtime.h>

// SelfAttention (Galerkin linear attention), round 8 (resubmit — R9/R10
// benches were GPUAcquisitionTimeout, no signal).
// Algebra: qk_in = x + pos ; K = qk_in Wk^T + bk ; V = x Wv^T + bv
//          (per-head LN on K,V) ; S'_h = K_h^T V_h / n
//          W2[he][r] = sum_d Wq[hd][r] S'[d][e] ; b2[he] = sum_d bq[hd] S'[d][e]
//          out = LN(2*(qk_in W2^T + b2)) stored NCHW.
// Kept: separable pos -> f32 tables; xT=bf16(x) XOR-swizzled; kv_scores with
//   swapped MFMA + wave-private relayout + split-K partials (R7: WRITE
//   303->141 MB, kv no longer dominant).
// R8: out_kernel was the new #1 (170us) and latency-bound:
//   VGPR 76 / no LDS -> 128 serial per-thread B-frag global loads, MfmaUtil
//   3.9%, 1.05 TB/s on a 178MB/28us roofline. Rewritten in kv_scores' image:
//   512 threads, 8 waves, NT=4 tiles; xT k-chunks staged via global_load_lds
//   (shared by all waves, dbuf); A = W2 oc-band frags (4 regs/kc, L2-hot),
//   B = x from LDS -> D[oc][n]. LN over 256 oc = in-lane + shfl(l4) +
//   cross-wave LDS partial reduction (padded, broadcast reads). Stores are
//   64B-coalesced scalars. posw2 re-lays Px2 as [j][oc] (r-indexed in-lane).

typedef float floatx4 __attribute__((ext_vector_type(4)));
typedef __bf16 bf16x8 __attribute__((ext_vector_type(8)));
typedef unsigned short ushortx8 __attribute__((ext_vector_type(8)));
typedef unsigned short ushort;

static __device__ __forceinline__ ushort f2bf(float f) {
  unsigned int u = __builtin_bit_cast(unsigned int, f);
  u += 0x7FFFu + ((u >> 16) & 1u);  // RNE
  return (ushort)(u >> 16);
}
static __device__ __forceinline__ float bf2f(ushort u) {
  unsigned int x = ((unsigned int)u) << 16;
  return __builtin_bit_cast(float, x);
}
static __device__ __forceinline__ floatx4 mfma16(bf16x8 a, bf16x8 b, floatx4 c) {
  return __builtin_amdgcn_mfma_f32_16x16x32_bf16(a, b, c, 0, 0, 0);
}
static __device__ __forceinline__ bf16x8 frag(const ushort* p) {
  return *(const bf16x8*)p;  // 16-B aligned by construction -> dwordx4
}
typedef __attribute__((address_space(3))) unsigned int as3_u32;
typedef __attribute__((address_space(1))) const unsigned int as1_u32;
static __device__ __forceinline__ void gl_lds16(const ushort* g, ushort* l) {
  __builtin_amdgcn_global_load_lds((as1_u32*)g, (as3_u32*)l, 16, 0, 0);
}

// ---------------------------------------------------------------------------
// Wk, Wv fp32 -> bf16 (plain [oc][256]).
__global__ __launch_bounds__(256) void prep_w(const float* __restrict__ Wk,
                                              const float* __restrict__ Wv,
                                              ushort* __restrict__ Wkbf,
                                              ushort* __restrict__ Wvbf) {
  const int i = (int)blockIdx.x * 256 + (int)threadIdx.x;
  float4 a = ((const float4*)Wk)[i];
  float4 b = ((const float4*)Wv)[i];
  ushort4 ua = {f2bf(a.x), f2bf(a.y), f2bf(a.z), f2bf(a.w)};
  ushort4 ub = {f2bf(b.x), f2bf(b.y), f2bf(b.z), f2bf(b.w)};
  ((ushort4*)Wkbf)[i] = ua;
  ((ushort4*)Wvbf)[i] = ub;
}

// ---------------------------------------------------------------------------
// Pos tables for K: PyKb[i][oc] = bk[oc] + sum_{kk<128} pe(i,kk)*Wk[oc][kk]
//                   PxKj[j][oc] =          sum_{kk<128} pe(j,kk)*Wk[oc][128+kk]
__global__ __launch_bounds__(256) void poswk(const float* __restrict__ Wk,
                                             const float* __restrict__ bk,
                                             float* __restrict__ PyKb,
                                             float* __restrict__ PxKj) {
  __shared__ float pe[128];
  const int ii = (int)blockIdx.x, t = (int)threadIdx.x;
  if (t < 128) {
    const float coord = (float)(ii + 1) * (6.283185307179586f / (128.0f + 1e-6f));
    const float inv = exp2f(-13.287712379549449f * (float)(t >> 1) * (1.0f / 64.0f));
    const float arg = coord * inv;
    pe[t] = (t & 1) ? cosf(arg) : sinf(arg);
  }
  __syncthreads();
  const float* wrow = Wk + (size_t)t * 256;
  float py = bk[t], px = 0.0f;
#pragma unroll 8
  for (int kk = 0; kk < 128; ++kk) {
    py += pe[kk] * wrow[kk];
    px += pe[kk] * wrow[128 + kk];
  }
  PyKb[ii * 256 + t] = py;
  PxKj[ii * 256 + t] = px;  // [j][oc]
}

// ---------------------------------------------------------------------------
// Pos tables for W2 (per z), from bf16 W2 (same quantization the GEMM uses):
//   Py2b[z][i][e] = b2[z][e] + pos_y(i) @ W2[z][e][:128]
//   Px2j[z][j][e] =            pos_x(j) @ W2[z][e][128:]   ([j][oc] layout, R8)
__global__ __launch_bounds__(256) void posw2(const ushort* __restrict__ W2bf,
                                             const float* __restrict__ b2,
                                             float* __restrict__ Py2b,
                                             float* __restrict__ Px2j) {
  __shared__ float pe[128];
  const int ii = (int)blockIdx.x, z = (int)blockIdx.y, t = (int)threadIdx.x;
  if (t < 128) {
    const float coord = (float)(ii + 1) * (6.283185307179586f / (128.0f + 1e-6f));
    const float inv = exp2f(-13.287712379549449f * (float)(t >> 1) * (1.0f / 64.0f));
    const float arg = coord * inv;
    pe[t] = (t & 1) ? cosf(arg) : sinf(arg);
  }
  __syncthreads();
  const ushort* wrow = W2bf + (size_t)z * 65536 + (size_t)t * 256;
  float py = b2[z * 256 + t], px = 0.0f;
#pragma unroll 8
  for (int kk = 0; kk < 128; ++kk) {
    py += pe[kk] * bf2f(wrow[kk]);
    px += pe[kk] * bf2f(wrow[128 + kk]);
  }
  Py2b[((size_t)z * 128 + ii) * 256 + t] = py;
  Px2j[((size_t)z * 128 + ii) * 256 + t] = px;  // [j][oc]
}

// ---------------------------------------------------------------------------
// For batch b0+z: xT[z][n][k] = bf16(x). SWIZZLED store: 16B sub-chunk p
// stored at p ^ (n&7) within each 64-k group.
__global__ __launch_bounds__(256) void prep_qx(const float* __restrict__ x,
                                               ushort* __restrict__ xT, int b0) {
  __shared__ float tile[64 * 68];
  const int t = (int)threadIdx.x;
  const int z = (int)blockIdx.y;
  const int b = b0 + z;
  const int n0 = (int)blockIdx.x * 64;
  const float* xb = x + (size_t)b * 256 * 16384;
  ushort* xtb = xT + (size_t)z * 16384 * 256;
  for (int kc = 0; kc < 4; ++kc) {
    if (kc) __syncthreads();
    const int nn = (t & 15) * 4;
    const int r0 = t >> 4;
#pragma unroll
    for (int it = 0; it < 4; ++it) {
      const int k = r0 + it * 16;
      const float4 v = *(const float4*)(xb + (size_t)(kc * 64 + k) * 16384 + n0 + nn);
      tile[(nn + 0) * 68 + k] = v.x;
      tile[(nn + 1) * 68 + k] = v.y;
      tile[(nn + 2) * 68 + k] = v.z;
      tile[(nn + 3) * 68 + k] = v.w;
    }
    __syncthreads();
#pragma unroll
    for (int it = 0; it < 2; ++it) {
      const int P = t + it * 256;
      const int r = P >> 3;  // n row 0..63
      const int p = P & 7;   // k chunk of 8
      const int n = n0 + r;
      ushortx8 ux;
#pragma unroll
      for (int e = 0; e < 8; ++e) ux[e] = f2bf(tile[r * 68 + p * 8 + e]);
      const int sw = (p ^ (r & 7)) * 8;
      *(ushortx8*)(xtb + (size_t)n * 256 + kc * 64 + sw) = ux;
    }
  }
}

// ---------------------------------------------------------------------------
// Per block: (NT x 128-n tiles, z); 8 waves, wave w = head w. xT read ONCE.
// SWAPPED MFMA: acc[tt][m] = mfma(Wfrag, xfrag) -> D[oc][n]:
//   oc = w*32 + tt*16 + l4*4 + r ; n = m*16 + l15.
// LN over 32 oc: in-lane (tt,r) adds + shfl_xor 16,32 across l4.
// KT/VT relayout wave-private (rows w*32..+32) -> no barriers.
// Output: plain-stored f32 partial tile per (z,h,bx) -> reduce_scores.
#define LDC2 40
#define NT 4
__global__ __launch_bounds__(512, 2) void kv_scores(
    const ushort* __restrict__ xT, const ushort* __restrict__ Wkbf,
    const ushort* __restrict__ Wvbf, const float* __restrict__ bv,
    const float* __restrict__ gK, const float* __restrict__ bKp,
    const float* __restrict__ gV, const float* __restrict__ bVp,
    const float* __restrict__ PyKb, const float* __restrict__ PxKj,
    float* __restrict__ partials) {
  __shared__ ushort SQ[2][128 * 64];  // staged xT k-chunks (swizzled), dbuf
  __shared__ ushort KT[256 * LDC2];   // wave-private 32-row bands
  __shared__ ushort VT[256 * LDC2];
  const int t = (int)threadIdx.x, lane = t & 63, w = t >> 6;  // w = head 0..7
  const int l15 = lane & 15, l4 = lane >> 4;
  const int z = (int)blockIdx.y;
  const int bx = (int)blockIdx.x;
  const ushort* xb = xT + (size_t)z * 16384 * 256;
  const int ocb = w * 32;
  const int h = w;
  const int oc4 = ocb + l4 * 4;  // base oc of this lane's r-quad (tt adds 16)
  // per-oc params, r-indexed float4 (in-lane after the swap)
  const floatx4 bv4[2] = {*(const floatx4*)(bv + oc4),
                          *(const floatx4*)(bv + oc4 + 16)};
  const int hb = h * 32 + l4 * 4;
  const floatx4 gk4[2] = {*(const floatx4*)(gK + hb), *(const floatx4*)(gK + hb + 16)};
  const floatx4 ok4[2] = {*(const floatx4*)(bKp + hb), *(const floatx4*)(bKp + hb + 16)};
  const floatx4 gv4[2] = {*(const floatx4*)(gV + hb), *(const floatx4*)(gV + hb + 16)};
  const floatx4 ov4[2] = {*(const floatx4*)(bVp + hb), *(const floatx4*)(bVp + hb + 16)};
  // staging: wave w copies rows [w*16, w*16+16), 8 rows per issue, 2 issues
  const int srow = w * 16 + (lane >> 3);
  const int scol = (lane & 7) * 8;
  const int rsw = l15 & 7;

  auto issue = [&](int s) {
    const int n0s = (bx * NT + (s >> 2)) * 128;
    const int kcs = (s & 3) * 64;
    ushort* dst = &SQ[s & 1][w * 1024];
    const ushort* src = xb + (size_t)(n0s + srow) * 256 + kcs + scol;
#pragma unroll
    for (int j = 0; j < 2; ++j) gl_lds16(src + (size_t)j * 8 * 256, dst + j * 512);
  };
  issue(0);

  floatx4 sacc[2][2] = {};
  for (int nt = 0; nt < NT; ++nt) {
    const int i_nt = bx * NT + nt;
    floatx4 acck[2][8] = {};
    floatx4 accv[2][8] = {};
    for (int kc = 0; kc < 4; ++kc) {
      const int s = nt * 4 + kc;
      __syncthreads();  // drains stage s; protects buf (s+1)&1 overwrite
      // A-frags (W rows, L1/L2-hot)
      bf16x8 Ak0[2], Ak1[2], Av0[2], Av1[2];
#pragma unroll
      for (int ci = 0; ci < 2; ++ci) {
        const int kb = (kc * 2 + ci) * 32 + l4 * 8;
        Ak0[ci] = frag(Wkbf + (ocb + l15) * 256 + kb);
        Ak1[ci] = frag(Wkbf + (ocb + 16 + l15) * 256 + kb);
        Av0[ci] = frag(Wvbf + (ocb + l15) * 256 + kb);
        Av1[ci] = frag(Wvbf + (ocb + 16 + l15) * 256 + kb);
      }
      if (s < NT * 4 - 1) issue(s + 1);  // drain lands at NEXT barrier
      const ushort* sq = &SQ[s & 1][0];
      __builtin_amdgcn_s_setprio(1);
#pragma unroll
      for (int ci = 0; ci < 2; ++ci) {
#pragma unroll
        for (int m = 0; m < 8; ++m) {
          const int off = (m * 16 + l15) * 64 + ((ci * 4 + l4) ^ rsw) * 8;
          const bf16x8 b = *(const bf16x8*)(sq + off);  // x-frag as B operand
          acck[0][m] = mfma16(Ak0[ci], b, acck[0][m]);
          acck[1][m] = mfma16(Ak1[ci], b, acck[1][m]);
          accv[0][m] = mfma16(Av0[ci], b, accv[0][m]);
          accv[1][m] = mfma16(Av1[ci], b, accv[1][m]);
        }
      }
      __builtin_amdgcn_s_setprio(0);
    }
    // pos-y table (per i-tile), r-indexed
    const floatx4 pyk[2] = {*(const floatx4*)(PyKb + i_nt * 256 + oc4),
                            *(const floatx4*)(PyKb + i_nt * 256 + oc4 + 16)};
    // LN + wave-private relayout + S-MFMA per 32-n quarter
#pragma unroll
    for (int q = 0; q < 4; ++q) {
#pragma unroll
      for (int mm = 0; mm < 2; ++mm) {
        const int m = q * 2 + mm;
        // K: add pos tables (pos-x per lane's n-col), then LN
        const floatx4 pxk0 = *(const floatx4*)(PxKj + (m * 16 + l15) * 256 + oc4);
        const floatx4 pxk1 = *(const floatx4*)(PxKj + (m * 16 + l15) * 256 + oc4 + 16);
        float s0 = 0.0f, q0 = 0.0f;
#pragma unroll
        for (int r = 0; r < 4; ++r) {
          acck[0][m][r] += pyk[0][r] + pxk0[r];
          acck[1][m][r] += pyk[1][r] + pxk1[r];
          const float v0 = acck[0][m][r], v1 = acck[1][m][r];
          s0 += v0 + v1;
          q0 += v0 * v0 + v1 * v1;
        }
        s0 += __shfl_xor(s0, 16); s0 += __shfl_xor(s0, 32);
        q0 += __shfl_xor(q0, 16); q0 += __shfl_xor(q0, 32);
        {
          const float mu = s0 * (1.0f / 32.0f);
          const float rstd = rsqrtf(q0 * (1.0f / 32.0f) - mu * mu + 1e-5f);
#pragma unroll
          for (int tt = 0; tt < 2; ++tt)
#pragma unroll
            for (int r = 0; r < 4; ++r)
              acck[tt][m][r] = (acck[tt][m][r] - mu) * rstd * gk4[tt][r] + ok4[tt][r];
        }
        // V: bias then LN
        float s1 = 0.0f, q1 = 0.0f;
#pragma unroll
        for (int r = 0; r < 4; ++r) {
          accv[0][m][r] += bv4[0][r];
          accv[1][m][r] += bv4[1][r];
          const float v0 = accv[0][m][r], v1 = accv[1][m][r];
          s1 += v0 + v1;
          q1 += v0 * v0 + v1 * v1;
        }
        s1 += __shfl_xor(s1, 16); s1 += __shfl_xor(s1, 32);
        q1 += __shfl_xor(q1, 16); q1 += __shfl_xor(q1, 32);
        {
          const float mu = s1 * (1.0f / 32.0f);
          const float rstd = rsqrtf(q1 * (1.0f / 32.0f) - mu * mu + 1e-5f);
#pragma unroll
          for (int tt = 0; tt < 2; ++tt)
#pragma unroll
            for (int r = 0; r < 4; ++r)
              accv[tt][m][r] = (accv[tt][m][r] - mu) * rstd * gv4[tt][r] + ov4[tt][r];
        }
        // wave-private relayout: KT[ch][ncol] b16 scatter (~2-way banks)
#pragma unroll
        for (int tt = 0; tt < 2; ++tt) {
          const int ch = w * 32 + tt * 16 + l4 * 4;
#pragma unroll
          for (int r = 0; r < 4; ++r) {
            KT[(ch + r) * LDC2 + mm * 16 + l15] = f2bf(acck[tt][m][r]);
            VT[(ch + r) * LDC2 + mm * 16 + l15] = f2bf(accv[tt][m][r]);
          }
        }
      }
      // S-MFMA on this quarter (in-wave lgkmcnt orders writes->reads)
      const int ko = l4 * 8;
      const bf16x8 ka0 = *(const bf16x8*)(KT + (w * 32 + l15) * LDC2 + ko);
      const bf16x8 ka1 = *(const bf16x8*)(KT + (w * 32 + 16 + l15) * LDC2 + ko);
      const bf16x8 vb0 = *(const bf16x8*)(VT + (w * 32 + l15) * LDC2 + ko);
      const bf16x8 vb1 = *(const bf16x8*)(VT + (w * 32 + 16 + l15) * LDC2 + ko);
      sacc[0][0] = mfma16(ka0, vb0, sacc[0][0]);
      sacc[0][1] = mfma16(ka0, vb1, sacc[0][1]);
      sacc[1][0] = mfma16(ka1, vb0, sacc[1][0]);
      sacc[1][1] = mfma16(ka1, vb1, sacc[1][1]);
    }
  }
  // plain coalesced partial store (no atomics)
  float* pp = partials + (((size_t)z * 8 + h) * 32 + bx) * 1024;
#pragma unroll
  for (int di = 0; di < 2; ++di)
#pragma unroll
    for (int ej = 0; ej < 2; ++ej)
#pragma unroll
      for (int r = 0; r < 4; ++r)
        pp[(di * 16 + l4 * 4 + r) * 32 + ej * 16 + l15] = sacc[di][ej][r];
}

// ---------------------------------------------------------------------------
// scores[z][h][d][e] = sum_bx partials[z][h][bx][d][e]  (raw sum; w2 scales)
__global__ __launch_bounds__(256) void reduce_scores(
    const float* __restrict__ partials, float* __restrict__ scores) {
  const int h = (int)blockIdx.x, z = (int)blockIdx.y, t = (int)threadIdx.x;
  const float* pb = partials + ((size_t)(z * 8 + h) * 32) * 1024 + t * 4;
  float4 s = {0.0f, 0.0f, 0.0f, 0.0f};
#pragma unroll 8
  for (int bx = 0; bx < 32; ++bx) {
    const float4 v = *(const float4*)(pb + bx * 1024);
    s.x += v.x; s.y += v.y; s.z += v.z; s.w += v.w;
  }
  *(float4*)(scores + (size_t)(z * 8 + h) * 1024 + t * 4) = s;
}

// ---------------------------------------------------------------------------
// W2bf[z][he][r] = sum_d Wq[hd][r] S'[d][e] / n ; b2 = bq-fold / n.
__global__ __launch_bounds__(256) void w2_kernel(
    const float* __restrict__ Wq, const float* __restrict__ bq,
    const float* __restrict__ scores, ushort* __restrict__ W2bf,
    float* __restrict__ b2) {
  const int z = (int)blockIdx.y;
  const int row = (int)blockIdx.x;
  const int t = (int)threadIdx.x;
  const float inv_n = 1.0f / 16384.0f;
  const float* sc = scores + (size_t)z * 8192;
  if (row < 256) {
    const int h = row >> 5, e = row & 31;
    float s = 0.0f;
#pragma unroll
    for (int d = 0; d < 32; ++d)
      s += Wq[(h * 32 + d) * 256 + t] * sc[(h * 32 + d) * 32 + e];
    W2bf[(size_t)z * 65536 + row * 256 + t] = f2bf(s * inv_n);
  } else {
    const int h = t >> 5, e = t & 31;
    float s = 0.0f;
#pragma unroll
    for (int d = 0; d < 32; ++d)
      s += bq[h * 32 + d] * sc[(h * 32 + d) * 32 + e];
    b2[z * 256 + t] = s * inv_n;
  }
}

// ---------------------------------------------------------------------------
// out = LN(2*(x W2^T + Py2[i] + Px2[j])) stored NCHW (b2 folded into Py2).
// kv_scores-style: 8 waves, wave w owns oc band w*32..+32; xT staged via
// global_load_lds (swizzled source, linear dest); A=W2 frags, B=x frags ->
// D[oc][n]. LN over 256 oc: in-lane + shfl(l4) + cross-wave LDS reduction.
#define ONT 4
__global__ __launch_bounds__(512, 2) void out_kernel(
    const ushort* __restrict__ xT, const ushort* __restrict__ W2bf,
    const float* __restrict__ Py2b, const float* __restrict__ Px2j,
    const float* __restrict__ g_ln, const float* __restrict__ b_ln,
    float* __restrict__ out, int b0) {
  __shared__ ushort SQ[2][128 * 64];  // staged xT k-chunks (swizzled), dbuf
  __shared__ float redS[8][136];      // per-wave LN partials (padded)
  __shared__ float redQ[8][136];
  const int t = (int)threadIdx.x, lane = t & 63, w = t >> 6;
  const int l15 = lane & 15, l4 = lane >> 4;
  const int z = (int)blockIdx.y, b = b0 + z;
  const int bx = (int)blockIdx.x;
  const ushort* xb = xT + (size_t)z * 16384 * 256;
  const ushort* W2b = W2bf + (size_t)z * 65536;
  const int ocb = w * 32;
  const int oc4 = ocb + l4 * 4;  // base oc of this lane's r-quad (tt adds 16)
  const floatx4 gl4[2] = {*(const floatx4*)(g_ln + oc4),
                          *(const floatx4*)(g_ln + oc4 + 16)};
  const floatx4 bl4[2] = {*(const floatx4*)(b_ln + oc4),
                          *(const floatx4*)(b_ln + oc4 + 16)};
  const int srow = w * 16 + (lane >> 3);
  const int scol = (lane & 7) * 8;
  const int rsw = l15 & 7;

  auto issue = [&](int s) {
    const int n0s = (bx * ONT + (s >> 2)) * 128;
    const int kcs = (s & 3) * 64;
    ushort* dst = &SQ[s & 1][w * 1024];
    const ushort* src = xb + (size_t)(n0s + srow) * 256 + kcs + scol;
#pragma unroll
    for (int j = 0; j < 2; ++j) gl_lds16(src + (size_t)j * 8 * 256, dst + j * 512);
  };
  issue(0);

  for (int nt = 0; nt < ONT; ++nt) {
    const int i_nt = bx * ONT + nt;
    const int n0 = i_nt * 128;
    floatx4 acc[2][8] = {};
    for (int kc = 0; kc < 4; ++kc) {
      const int s = nt * 4 + kc;
      __syncthreads();  // drains stage s; protects buf (s+1)&1 overwrite
      bf16x8 A0[2], A1[2];  // W2 oc-band frags (L2-hot)
#pragma unroll
      for (int ci = 0; ci < 2; ++ci) {
        const int kb = (kc * 2 + ci) * 32 + l4 * 8;
        A0[ci] = frag(W2b + (ocb + l15) * 256 + kb);
        A1[ci] = frag(W2b + (ocb + 16 + l15) * 256 + kb);
      }
      if (s < ONT * 4 - 1) issue(s + 1);  // drain lands at NEXT barrier
      const ushort* sq = &SQ[s & 1][0];
      __builtin_amdgcn_s_setprio(1);
#pragma unroll
      for (int ci = 0; ci < 2; ++ci) {
#pragma unroll
        for (int m = 0; m < 8; ++m) {
          const int off = (m * 16 + l15) * 64 + ((ci * 4 + l4) ^ rsw) * 8;
          const bf16x8 bb = *(const bf16x8*)(sq + off);
          acc[0][m] = mfma16(A0[ci], bb, acc[0][m]);
          acc[1][m] = mfma16(A1[ci], bb, acc[1][m]);
        }
      }
      __builtin_amdgcn_s_setprio(0);
    }
    // + pos tables (b2 folded in Py2), x2, per-wave LN partials
    const floatx4 py[2] = {
        *(const floatx4*)(Py2b + ((size_t)z * 128 + i_nt) * 256 + oc4),
        *(const floatx4*)(Py2b + ((size_t)z * 128 + i_nt) * 256 + oc4 + 16)};
#pragma unroll
    for (int m = 0; m < 8; ++m) {
      const float* pxr = Px2j + ((size_t)z * 128 + m * 16 + l15) * 256;
      const floatx4 px0 = *(const floatx4*)(pxr + oc4);
      const floatx4 px1 = *(const floatx4*)(pxr + oc4 + 16);
      float s = 0.0f, q = 0.0f;
#pragma unroll
      for (int r = 0; r < 4; ++r) {
        const float v0 = 2.0f * (acc[0][m][r] + py[0][r] + px0[r]);
        const float v1 = 2.0f * (acc[1][m][r] + py[1][r] + px1[r]);
        acc[0][m][r] = v0;
        acc[1][m][r] = v1;
        s += v0 + v1;
        q += v0 * v0 + v1 * v1;
      }
      s += __shfl_xor(s, 16); s += __shfl_xor(s, 32);
      q += __shfl_xor(q, 16); q += __shfl_xor(q, 32);
      if (l4 == 0) {
        redS[w][m * 16 + l15] = s;
        redQ[w][m * 16 + l15] = q;
      }
    }
    __syncthreads();  // partials visible to all waves
    // cross-wave LN + coalesced scalar stores (64B segments per l4-group)
#pragma unroll
    for (int m = 0; m < 8; ++m) {
      const int nr = m * 16 + l15;
      float S = 0.0f, Q = 0.0f;
#pragma unroll
      for (int ww = 0; ww < 8; ++ww) {
        S += redS[ww][nr];  // broadcast reads across l4
        Q += redQ[ww][nr];
      }
      const float mu = S * (1.0f / 256.0f);
      const float rstd = rsqrtf(Q * (1.0f / 256.0f) - mu * mu + 1e-5f);
#pragma unroll
      for (int tt = 0; tt < 2; ++tt)
#pragma unroll
        for (int r = 0; r < 4; ++r) {
          const float o = (acc[tt][m][r] - mu) * rstd * gl4[tt][r] + bl4[tt][r];
          out[(size_t)(b * 256 + oc4 + tt * 16 + r) * 16384 + n0 + nr] = o;
        }
    }
    // red arrays rewritten only after the next nt's 4 kc-barriers -> safe
  }
}

// ---------------------------------------------------------------------------
extern "C" void kernel_launch(void* const* d_in, const int* in_sizes, int n_in,
                              void* d_out, int out_size, void* d_ws, size_t ws_size,
                              hipStream_t stream) {
  (void)in_sizes; (void)n_in; (void)out_size;
  const float* x   = (const float*)d_in[0];
  const float* Wq  = (const float*)d_in[1];
  const float* bq  = (const float*)d_in[2];
  const float* Wk  = (const float*)d_in[3];
  const float* bk  = (const float*)d_in[4];
  const float* Wv  = (const float*)d_in[5];
  const float* bv  = (const float*)d_in[6];
  const float* gK  = (const float*)d_in[7];
  const float* bK  = (const float*)d_in[8];
  const float* gV  = (const float*)d_in[9];
  const float* bV  = (const float*)d_in[10];
  const float* gln = (const float*)d_in[11];
  const float* bln = (const float*)d_in[12];
  float* out = (float*)d_out;

  // Per-batch: xT 8MB + W2bf 128K + Py2 128K + Px2 128K + partials 1MB
  //            + scores 32K + b2 1K = 9,864,192 B.
  // Shared: Wk/Wv bf 256K + K-tables 256K. g=8 -> 79.4 MB; halves if needed.
  const size_t PB = 16384ULL * 256 * 2;
  const size_t PERZ = PB + 131072 + 131072 + 131072 + 1048576 + 32768 + 1024;
  const size_t SHARED = 262144 + 262144;
  int g = 8;
  while (g > 1 && ws_size < (size_t)g * PERZ + SHARED) g >>= 1;
  // g=1 needs 10,388,480 B <= proven-safe 18,096,128 B.

  char* p = (char*)d_ws;
  ushort* xT    = (ushort*)p; p += (size_t)g * PB;
  ushort* Wkbf  = (ushort*)p; p += 131072;
  ushort* Wvbf  = (ushort*)p; p += 131072;
  float*  PyKb  = (float*)p;  p += 131072;
  float*  PxKj  = (float*)p;  p += 131072;
  ushort* W2bf  = (ushort*)p; p += (size_t)g * 131072;
  float*  Py2b  = (float*)p;  p += (size_t)g * 131072;
  float*  Px2j  = (float*)p;  p += (size_t)g * 131072;
  float*  partials = (float*)p; p += (size_t)g * 1048576;
  float*  scores = (float*)p; p += (size_t)g * 32768;
  float*  b2    = (float*)p;

  prep_w<<<dim3(64), 256, 0, stream>>>(Wk, Wv, Wkbf, Wvbf);
  poswk<<<dim3(128), 256, 0, stream>>>(Wk, bk, PyKb, PxKj);
  for (int b0 = 0; b0 < 8; b0 += g) {
    prep_qx<<<dim3(256, g), 256, 0, stream>>>(x, xT, b0);
    kv_scores<<<dim3(32, g), 512, 0, stream>>>(xT, Wkbf, Wvbf, bv, gK, bK,
                                               gV, bV, PyKb, PxKj, partials);
    reduce_scores<<<dim3(8, g), 256, 0, stream>>>(partials, scores);
    w2_kernel<<<dim3(257, g), 256, 0, stream>>>(Wq, bq, scores, W2bf, b2);
    posw2<<<dim3(128, g), 256, 0, stream>>>(W2bf, b2, Py2b, Px2j);
    out_kernel<<<dim3(32, g), 512, 0, stream>>>(xT, W2bf, Py2b, Px2j, gln, bln,
                                                out, b0);
  }
}